// Round 8
// baseline (668.537 us; speedup 1.0000x reference)
//
#include <hip/hip_runtime.h>
#include <hip/hip_bf16.h>
#include <stdint.h>

typedef __attribute__((ext_vector_type(8))) short short8;
typedef __attribute__((ext_vector_type(16))) float floatx16;
typedef unsigned short u16;

#define IN_DIM  1024
#define OUT_DIM 1024
#define NG      11            // spline bases per channel
#define GK      12            // + silu slot
#define KDIM    (IN_DIM * GK) // 12288
#define TOKENS  8192
#define MT      64            // M tiles (8192/128)
#define BK      96            // 8 channels x 12 slots = 6 k-steps of 16
#define PB      104           // padded LDS row stride (u16). PB/8=13 odd -> granule stride 1 mod 8
                              // -> 8-lane phases hit 8 distinct bank-groups: conflict-free r/w

__device__ __forceinline__ u16 f2bf(float f) {
  uint32_t u = __float_as_uint(f);
  uint32_t r = (u + 0x7fffu + ((u >> 16) & 1u)) >> 16;  // RNE
  return (u16)r;
}

// ---------------- pack Wt: bf16 [OUT_DIM][KDIM] (R5 coalesced version)
__global__ __launch_bounds__(256) void pack_wt_kernel(
    const float* __restrict__ coeff, const float* __restrict__ sb,
    const float* __restrict__ ss_p, u16* __restrict__ Wt)
{
  __shared__ float cf[256 * NG];
  __shared__ __align__(16) u16 st[256 * GK];
  const int tid = threadIdx.x;
  const int b   = blockIdx.x;
  const int o   = b >> 2;
  const int i0  = (b & 3) * 256;
  const float* cbase = coeff + (size_t)o * (IN_DIM * NG) + (size_t)i0 * NG;
#pragma unroll
  for (int p = 0; p < NG; ++p) cf[p * 256 + tid] = cbase[p * 256 + tid];
  const float ss  = ss_p[0];
  const float sbv = sb[(size_t)o * IN_DIM + i0 + tid];
  __syncthreads();
  const float* cp = cf + tid * NG;
  u16 h[GK];
#pragma unroll
  for (int g = 0; g < NG; ++g) h[g] = f2bf(cp[g] * ss);
  h[NG] = f2bf(sbv);
  uint64_t V0 = (uint64_t)h[0] | ((uint64_t)h[1] << 16) | ((uint64_t)h[2] << 32) | ((uint64_t)h[3] << 48);
  uint64_t V1 = (uint64_t)h[4] | ((uint64_t)h[5] << 16) | ((uint64_t)h[6] << 32) | ((uint64_t)h[7] << 48);
  uint64_t V2 = (uint64_t)h[8] | ((uint64_t)h[9] << 16) | ((uint64_t)h[10] << 32) | ((uint64_t)h[11] << 48);
  uint64_t* sp = (uint64_t*)(st + tid * GK);
  sp[0] = V0; sp[1] = V1; sp[2] = V2;
  __syncthreads();
  const uint4* src = (const uint4*)st;
  uint4* dst = (uint4*)(Wt + (size_t)b * (256 * GK));
  dst[tid] = src[tid];
  if (tid < 128) dst[256 + tid] = src[256 + tid];
}

// Closed-form cubic B-spline + silu -> 3 u64 (24B group), register funnel placement.
// Byte-identical math to R4's verified expand kernel (absmax 0.125).
__device__ __forceinline__ void expand_regs(float x, float g0, float inv_h,
                                            uint64_t& V0, uint64_t& V1, uint64_t& V2)
{
  float t  = (x - g0) * inv_h;
  float fc = floorf(t);
  int   c  = (int)fc;
  float u  = t - fc;
  float u2 = u * u;
  float w1 = 1.0f - u;
  float b0 = (w1 * w1 * w1) * (1.0f / 6.0f);
  float b1 = (0.5f * u - 1.0f) * u2 + (2.0f / 3.0f);
  float b2 = ((-0.5f * u + 0.5f) * u + 0.5f) * u + (1.0f / 6.0f);
  float b3 = (u2 * u) * (1.0f / 6.0f);
  float sil = x / (1.0f + __expf(-x));

  uint64_t P = (uint64_t)f2bf(b0) | ((uint64_t)f2bf(b1) << 16)
             | ((uint64_t)f2bf(b2) << 32) | ((uint64_t)f2bf(b3) << 48);
  int  k  = c - 3;
  bool cv = (c >= 0) && (c <= 13);
  int  kneg = (k < 0) ? -k : 0;
  uint64_t Pc = cv ? (P >> (16 * kneg)) : 0ull;
  uint32_t sh = (uint32_t)(16 * ((k < 0) ? 0 : k));

  V0 = (sh < 64)  ? (Pc << (sh & 63)) : 0ull;
  V1 = (sh == 0)  ? 0ull :
       (sh < 64)  ? (Pc >> ((64 - sh) & 63)) :
       (sh < 128) ? (Pc << ((sh - 64) & 63)) : 0ull;
  V2 = (sh <= 64) ? 0ull :
       (sh < 128) ? (Pc >> ((128 - sh) & 63)) :
                    (Pc << ((sh - 128) & 63));
  V2 = (V2 & 0x0000FFFFFFFFFFFFull) | ((uint64_t)f2bf(sil) << 48);
}

// ---------------- fused GEMM: out[8192,1024] = expand(x) * Wt^T
// 32x32x16 MFMA 2x2/wave, BK=96, PB=104 padded LDS (conflict-free), split-K via nsplit,
// VGPR-staged B, VALU-expanded A. blockIdx ≡ bm (mod 8) -> x/out strips XCD-local.
__global__ __launch_bounds__(256, 3) void gemm_fused_kernel(
    const float* __restrict__ X, const float* __restrict__ grid,
    const u16* __restrict__ Wt, float* __restrict__ out, float* __restrict__ part,
    int k_iters)   // channels per split = k_iters*8
{
  __shared__ __align__(16) u16 As[128 * PB];   // 26624 B
  __shared__ __align__(16) u16 Bs[128 * PB];   // 26624 B

  const int tid  = threadIdx.x;
  const int lane = tid & 63;
  const int wave = tid >> 6;
  const int mt8  = MT * 8;
  const int s    = blockIdx.x / mt8;
  const int r    = blockIdx.x - s * mt8;
  const int bm   = r % MT;
  const int bn   = r / MT;
  const int wm = (wave >> 1) * 64;
  const int wn = (wave & 1) * 64;

  const float g0    = grid[0];
  const float inv_h = 1.0f / (grid[1] - grid[0]);   // uniform grid

  floatx16 acc[2][2];
#pragma unroll
  for (int a = 0; a < 2; ++a)
#pragma unroll
    for (int b = 0; b < 2; ++b)
#pragma unroll
      for (int rr = 0; rr < 16; ++rr) acc[a][b][rr] = 0.f;

  // --- B staging: 1536 granules (128 rows x 12 chunks of 16B), 6 per thread.
  // Thread t, j: granule q = t + j*256 -> coalesced global reads; LDS at row*PB + chunk*8.
  const int kb_u16 = s * k_iters * BK;   // split's K base (u16 units)
  const u16* bgp[6];
  uint4*     blp[6];
#pragma unroll
  for (int j = 0; j < 6; ++j) {
    int q  = tid + j * 256;
    int rb = q / 12;
    int cb = q - rb * 12;
    bgp[j] = Wt + (size_t)(bn * 128 + rb) * KDIM + kb_u16 + cb * 8;
    blp[j] = (uint4*)(Bs + rb * PB + cb * 8);
  }

  // --- A expansion: thread -> (row, 4 channels). Writes 96B (6 b128) at row*208 + half*96.
  const int arow = tid & 127;
  const int half = tid >> 7;
  const float* xp = X + (size_t)(bm * 128 + arow) * IN_DIM + s * (k_iters * 8) + half * 4;
  uint4* awp = (uint4*)(As + arow * PB + half * 48);

  const int l31 = lane & 31;
  const int g   = lane >> 5;

  for (int it = 0; it < k_iters; ++it) {
    // B tile global loads first (latency hides under expansion VALU)
    uint4 bv[6];
#pragma unroll
    for (int j = 0; j < 6; ++j) { bv[j] = *(const uint4*)bgp[j]; bgp[j] += BK; }

    // A: expand this thread's 4 channels into 12 u64 in registers
    float4 xv = *(const float4*)(xp + it * 8);
    uint64_t ev[12];
    expand_regs(xv.x, g0, inv_h, ev[0], ev[1], ev[2]);
    expand_regs(xv.y, g0, inv_h, ev[3], ev[4], ev[5]);
    expand_regs(xv.z, g0, inv_h, ev[6], ev[7], ev[8]);
    expand_regs(xv.w, g0, inv_h, ev[9], ev[10], ev[11]);

    __syncthreads();   // all waves done reading previous tile

#pragma unroll
    for (int j = 0; j < 6; ++j) {
      uint4 w;
      w.x = (uint32_t)ev[2*j];     w.y = (uint32_t)(ev[2*j] >> 32);
      w.z = (uint32_t)ev[2*j+1];   w.w = (uint32_t)(ev[2*j+1] >> 32);
      awp[j] = w;
    }
#pragma unroll
    for (int j = 0; j < 6; ++j) *blp[j] = bv[j];

    __syncthreads();   // tiles complete

#pragma unroll
    for (int t = 0; t < 6; ++t) {        // 6 k-steps of 16
      const int cc = 2 * t + g;          // 16B chunk index (no XOR needed: PB does the swizzle)
      short8 af[2], bf[2];
#pragma unroll
      for (int ss2 = 0; ss2 < 2; ++ss2) {
        af[ss2] = *(const short8*)&As[(wm + ss2 * 32 + l31) * PB + cc * 8];
        bf[ss2] = *(const short8*)&Bs[(wn + ss2 * 32 + l31) * PB + cc * 8];
      }
#pragma unroll
      for (int sm = 0; sm < 2; ++sm)
#pragma unroll
        for (int sn = 0; sn < 2; ++sn)
          acc[sm][sn] = __builtin_amdgcn_mfma_f32_32x32x16_bf16(af[sm], bf[sn], acc[sm][sn], 0, 0, 0);
    }
  }
  __syncthreads();

  // C/D map (m74/m101-verified): col=lane&31, row=(reg&3)+8*(reg>>2)+4*(lane>>5)
  float* op = (s == 0) ? out : part;
#pragma unroll
  for (int sm = 0; sm < 2; ++sm)
#pragma unroll
    for (int sn = 0; sn < 2; ++sn) {
      const int row0 = bm * 128 + wm + sm * 32 + 4 * g;
      const int col  = bn * 128 + wn + sn * 32 + l31;
#pragma unroll
      for (int reg = 0; reg < 16; ++reg) {
        int row = row0 + (reg & 3) + 8 * (reg >> 2);
        op[(size_t)row * OUT_DIM + col] = acc[sm][sn][reg];
      }
    }
}

// out += part, float4-vectorized
__global__ __launch_bounds__(256) void reduce_kernel(
    float* __restrict__ out, const float* __restrict__ part)
{
  size_t i = (size_t)blockIdx.x * 256 + threadIdx.x;
  float4* o = (float4*)out;
  const float4* p = (const float4*)part;
  float4 a = o[i], b = p[i];
  a.x += b.x; a.y += b.y; a.z += b.z; a.w += b.w;
  o[i] = a;
}

extern "C" void kernel_launch(void* const* d_in, const int* in_sizes, int n_in,
                              void* d_out, int out_size, void* d_ws, size_t ws_size,
                              hipStream_t stream) {
  const float* x     = (const float*)d_in[0];
  const float* grid  = (const float*)d_in[1];
  const float* coeff = (const float*)d_in[2];
  const float* sb    = (const float*)d_in[3];
  const float* ss    = (const float*)d_in[4];
  float* out = (float*)d_out;

  u16* Wt = (u16*)d_ws;
  const size_t wt_bytes   = (size_t)OUT_DIM * KDIM * 2;     // 25.2 MB
  const size_t part_bytes = (size_t)TOKENS * OUT_DIM * 4;   // 33.6 MB
  float* part = (float*)((char*)d_ws + wt_bytes);

  pack_wt_kernel<<<(OUT_DIM * IN_DIM) / 256, 256, 0, stream>>>(coeff, sb, ss, Wt);

  if (ws_size >= wt_bytes + part_bytes) {
    // split-K=2: 1024 blocks; LDS 53.2KB -> 3 blocks/CU, 12 waves/CU
    gemm_fused_kernel<<<MT * 8 * 2, 256, 0, stream>>>(x, grid, Wt, out, part, 64);
    reduce_kernel<<<(TOKENS * OUT_DIM / 4) / 256, 256, 0, stream>>>(out, part);
  } else {
    // fallback: no split (s==0 for all blocks -> writes out directly), full K per block
    gemm_fused_kernel<<<MT * 8, 256, 0, stream>>>(x, grid, Wt, out, nullptr, 128);
  }
}

// Round 9
// 411.574 us; speedup vs baseline: 1.6243x; 1.6243x over previous
//
#include <hip/hip_runtime.h>
#include <hip/hip_bf16.h>
#include <stdint.h>

typedef __attribute__((ext_vector_type(8))) short short8;
typedef __attribute__((ext_vector_type(16))) float floatx16;
typedef unsigned short u16;

#define IN_DIM  1024
#define OUT_DIM 1024
#define NG      11            // spline bases per channel
#define GK      12            // + silu slot
#define KDIM    (IN_DIM * GK) // 12288
#define TOKENS  8192
#define MT      64            // M tiles (8192/128)
#define BK      96            // 8 channels x 12 slots = 6 k-steps of 16
#define PB      104           // padded LDS row stride (u16); 13 granules/row, 13 odd -> full
                              // bank-group rotation (R8: conflicts 2.5e7 -> 4.2e6)
#define NOPS    26            // B DMA ops/iter: 128 rows x 13 granules / 64 lanes

__device__ __forceinline__ u16 f2bf(float f) {
  uint32_t u = __float_as_uint(f);
  uint32_t r = (u + 0x7fffu + ((u >> 16) & 1u)) >> 16;  // RNE
  return (u16)r;
}

// ---------------- pack Wt: bf16 [OUT_DIM][KDIM] (R5 coalesced version)
__global__ __launch_bounds__(256) void pack_wt_kernel(
    const float* __restrict__ coeff, const float* __restrict__ sb,
    const float* __restrict__ ss_p, u16* __restrict__ Wt)
{
  __shared__ float cf[256 * NG];
  __shared__ __align__(16) u16 st[256 * GK];
  const int tid = threadIdx.x;
  const int b   = blockIdx.x;
  const int o   = b >> 2;
  const int i0  = (b & 3) * 256;
  const float* cbase = coeff + (size_t)o * (IN_DIM * NG) + (size_t)i0 * NG;
#pragma unroll
  for (int p = 0; p < NG; ++p) cf[p * 256 + tid] = cbase[p * 256 + tid];
  const float ss  = ss_p[0];
  const float sbv = sb[(size_t)o * IN_DIM + i0 + tid];
  __syncthreads();
  const float* cp = cf + tid * NG;
  u16 h[GK];
#pragma unroll
  for (int g = 0; g < NG; ++g) h[g] = f2bf(cp[g] * ss);
  h[NG] = f2bf(sbv);
  uint64_t V0 = (uint64_t)h[0] | ((uint64_t)h[1] << 16) | ((uint64_t)h[2] << 32) | ((uint64_t)h[3] << 48);
  uint64_t V1 = (uint64_t)h[4] | ((uint64_t)h[5] << 16) | ((uint64_t)h[6] << 32) | ((uint64_t)h[7] << 48);
  uint64_t V2 = (uint64_t)h[8] | ((uint64_t)h[9] << 16) | ((uint64_t)h[10] << 32) | ((uint64_t)h[11] << 48);
  uint64_t* sp = (uint64_t*)(st + tid * GK);
  sp[0] = V0; sp[1] = V1; sp[2] = V2;
  __syncthreads();
  const uint4* src = (const uint4*)st;
  uint4* dst = (uint4*)(Wt + (size_t)b * (256 * GK));
  dst[tid] = src[tid];
  if (tid < 128) dst[256 + tid] = src[256 + tid];
}

// Closed-form cubic B-spline + silu -> 3 u64, register funnel placement (verified, absmax 0.125)
__device__ __forceinline__ void expand_regs(float x, float g0, float inv_h,
                                            uint64_t& V0, uint64_t& V1, uint64_t& V2)
{
  float t  = (x - g0) * inv_h;
  float fc = floorf(t);
  int   c  = (int)fc;
  float u  = t - fc;
  float u2 = u * u;
  float w1 = 1.0f - u;
  float b0 = (w1 * w1 * w1) * (1.0f / 6.0f);
  float b1 = (0.5f * u - 1.0f) * u2 + (2.0f / 3.0f);
  float b2 = ((-0.5f * u + 0.5f) * u + 0.5f) * u + (1.0f / 6.0f);
  float b3 = (u2 * u) * (1.0f / 6.0f);
  float sil = x / (1.0f + __expf(-x));

  uint64_t P = (uint64_t)f2bf(b0) | ((uint64_t)f2bf(b1) << 16)
             | ((uint64_t)f2bf(b2) << 32) | ((uint64_t)f2bf(b3) << 48);
  int  k  = c - 3;
  bool cv = (c >= 0) && (c <= 13);
  int  kneg = (k < 0) ? -k : 0;
  uint64_t Pc = cv ? (P >> (16 * kneg)) : 0ull;
  uint32_t sh = (uint32_t)(16 * ((k < 0) ? 0 : k));

  V0 = (sh < 64)  ? (Pc << (sh & 63)) : 0ull;
  V1 = (sh == 0)  ? 0ull :
       (sh < 64)  ? (Pc >> ((64 - sh) & 63)) :
       (sh < 128) ? (Pc << ((sh - 64) & 63)) : 0ull;
  V2 = (sh <= 64) ? 0ull :
       (sh < 128) ? (Pc >> ((128 - sh) & 63)) :
                    (Pc << ((sh - 128) & 63));
  V2 = (V2 & 0x0000FFFFFFFFFFFFull) | ((uint64_t)f2bf(sil) << 48);
}

__device__ __forceinline__ void async16(const u16* g, u16* l) {
  __builtin_amdgcn_global_load_lds(
      (const __attribute__((address_space(1))) uint32_t*)g,
      (__attribute__((address_space(3))) uint32_t*)l,
      16, 0, 0);
}

// ---------------- fused GEMM: out[8192,1024] = expand(x) * Wt^T
// 32x32x16 MFMA 2x2/wave, BK=96, PB=104 padded LDS. B staged by DMA (pad-granule trick:
// Bs = 1664 contiguous granules, granule 13r+12 is pad -> lane reads a harmless dup).
// A staged by VALU expansion (no bv[] register stage -> kills R8's 64B/thread/iter spill).
// blockIdx ≡ bm (mod 8) -> x/out strips XCD-local.
__global__ __launch_bounds__(256, 3) void gemm_fused_kernel(
    const float* __restrict__ X, const float* __restrict__ grid,
    const u16* __restrict__ Wt, float* __restrict__ out, float* __restrict__ part,
    int k_iters)   // channels per split = k_iters*8
{
  __shared__ __align__(16) u16 As[128 * PB];   // 26624 B
  __shared__ __align__(16) u16 Bs[128 * PB];   // 26624 B

  const int tid  = threadIdx.x;
  const int lane = tid & 63;
  const int wave = tid >> 6;
  const int mt8  = MT * 8;
  const int s    = blockIdx.x / mt8;
  const int r    = blockIdx.x - s * mt8;
  const int bm   = r % MT;
  const int bn   = r / MT;
  const int wm = (wave >> 1) * 64;
  const int wn = (wave & 1) * 64;

  const float g0    = grid[0];
  const float inv_h = 1.0f / (grid[1] - grid[0]);   // uniform grid

  floatx16 acc[2][2];
#pragma unroll
  for (int a = 0; a < 2; ++a)
#pragma unroll
    for (int b = 0; b < 2; ++b)
#pragma unroll
      for (int rr = 0; rr < 16; ++rr) acc[a][b][rr] = 0.f;

  // --- B DMA setup: op o (o = wave + 4j, o < 26) moves granules [64o, 64o+64) of the tile.
  // lane: gidx = 64o+lane; row = gidx/13; chunk = gidx%13; chunk 12 = pad -> dup chunk 0.
  const int kb_u16 = s * k_iters * BK;
  const u16* bsrc[7];
  u16*       bdst[7];
  bool       bact[7];
#pragma unroll
  for (int j = 0; j < 7; ++j) {
    int o  = wave + 4 * j;
    bact[j] = (o < NOPS);
    int oc = bact[j] ? o : (NOPS - 1);
    int gidx  = oc * 64 + lane;
    int row   = gidx / 13;
    int chunk = gidx - row * 13;
    int c8    = (chunk == 12) ? 0 : chunk;
    bsrc[j] = Wt + (size_t)(bn * 128 + row) * KDIM + kb_u16 + c8 * 8;
    bdst[j] = Bs + oc * 512;   // 64 granules = 1024 B = 512 u16 per op
  }

  // --- A expansion: thread -> (row, 4 channels); writes 6 b128 at row*PB + half*48
  const int arow = tid & 127;
  const int half = tid >> 7;
  const float* xp = X + (size_t)(bm * 128 + arow) * IN_DIM + s * (k_iters * 8) + half * 4;
  uint4* awp = (uint4*)(As + arow * PB + half * 48);

  const int l31 = lane & 31;
  const int g   = lane >> 5;

  float4 xv = *(const float4*)xp;   // prefetched for it=0

  for (int it = 0; it < k_iters; ++it) {
    // expand this iter's 4 channels (VALU, overlaps other blocks' MFMA)
    uint64_t ev[12];
    expand_regs(xv.x, g0, inv_h, ev[0], ev[1], ev[2]);
    expand_regs(xv.y, g0, inv_h, ev[3], ev[4], ev[5]);
    expand_regs(xv.z, g0, inv_h, ev[6], ev[7], ev[8]);
    expand_regs(xv.w, g0, inv_h, ev[9], ev[10], ev[11]);
    if (it + 1 < k_iters) xv = *(const float4*)(xp + (size_t)(it + 1) * 8);

    __syncthreads();   // all waves done reading previous tile

    // B: DMA direct to LDS (no registers held)
#pragma unroll
    for (int j = 0; j < 7; ++j)
      if (bact[j]) async16(bsrc[j] + (size_t)it * BK, bdst[j]);

    // A: LDS writes from expansion registers
#pragma unroll
    for (int j = 0; j < 6; ++j) {
      uint4 w;
      w.x = (uint32_t)ev[2*j];     w.y = (uint32_t)(ev[2*j] >> 32);
      w.z = (uint32_t)ev[2*j+1];   w.w = (uint32_t)(ev[2*j+1] >> 32);
      awp[j] = w;
    }

    __syncthreads();   // vmcnt+lgkmcnt drained -> tiles complete

#pragma unroll
    for (int t = 0; t < 6; ++t) {        // 6 k-steps of 16
      const int cc = 2 * t + g;          // PB's odd granule stride does the de-conflicting
      short8 af[2], bf[2];
#pragma unroll
      for (int ss2 = 0; ss2 < 2; ++ss2) {
        af[ss2] = *(const short8*)&As[(wm + ss2 * 32 + l31) * PB + cc * 8];
        bf[ss2] = *(const short8*)&Bs[(wn + ss2 * 32 + l31) * PB + cc * 8];
      }
#pragma unroll
      for (int sm = 0; sm < 2; ++sm)
#pragma unroll
        for (int sn = 0; sn < 2; ++sn)
          acc[sm][sn] = __builtin_amdgcn_mfma_f32_32x32x16_bf16(af[sm], bf[sn], acc[sm][sn], 0, 0, 0);
    }
  }
  __syncthreads();

  // C/D map (m74/m101-verified): col=lane&31, row=(reg&3)+8*(reg>>2)+4*(lane>>5)
  float* op = (s == 0) ? out : part;
#pragma unroll
  for (int sm = 0; sm < 2; ++sm)
#pragma unroll
    for (int sn = 0; sn < 2; ++sn) {
      const int row0 = bm * 128 + wm + sm * 32 + 4 * g;
      const int col  = bn * 128 + wn + sn * 32 + l31;
#pragma unroll
      for (int reg = 0; reg < 16; ++reg) {
        int row = row0 + (reg & 3) + 8 * (reg >> 2);
        op[(size_t)row * OUT_DIM + col] = acc[sm][sn][reg];
      }
    }
}

// out += part, float4-vectorized
__global__ __launch_bounds__(256) void reduce_kernel(
    float* __restrict__ out, const float* __restrict__ part)
{
  size_t i = (size_t)blockIdx.x * 256 + threadIdx.x;
  float4* o = (float4*)out;
  const float4* p = (const float4*)part;
  float4 a = o[i], b = p[i];
  a.x += b.x; a.y += b.y; a.z += b.z; a.w += b.w;
  o[i] = a;
}

extern "C" void kernel_launch(void* const* d_in, const int* in_sizes, int n_in,
                              void* d_out, int out_size, void* d_ws, size_t ws_size,
                              hipStream_t stream) {
  const float* x     = (const float*)d_in[0];
  const float* grid  = (const float*)d_in[1];
  const float* coeff = (const float*)d_in[2];
  const float* sb    = (const float*)d_in[3];
  const float* ss    = (const float*)d_in[4];
  float* out = (float*)d_out;

  u16* Wt = (u16*)d_ws;
  const size_t wt_bytes   = (size_t)OUT_DIM * KDIM * 2;     // 25.2 MB
  const size_t part_bytes = (size_t)TOKENS * OUT_DIM * 4;   // 33.6 MB
  float* part = (float*)((char*)d_ws + wt_bytes);

  pack_wt_kernel<<<(OUT_DIM * IN_DIM) / 256, 256, 0, stream>>>(coeff, sb, ss, Wt);

  if (ws_size >= wt_bytes + part_bytes) {
    // split-K=2: 1024 blocks; LDS 53.2KB -> 3 blocks/CU, 12 waves/CU
    gemm_fused_kernel<<<MT * 8 * 2, 256, 0, stream>>>(x, grid, Wt, out, part, 64);
    reduce_kernel<<<(TOKENS * OUT_DIM / 4) / 256, 256, 0, stream>>>(out, part);
  } else {
    // fallback: no split (s==0 -> writes out directly), full K per block
    gemm_fused_kernel<<<MT * 8, 256, 0, stream>>>(x, grid, Wt, out, nullptr, 128);
  }
}